// Round 2
// baseline (197.227 us; speedup 1.0000x reference)
//
#include <hip/hip_runtime.h>
#include <stdint.h>

#define HWPOS 1024
#define CCH   256
#define RROWS 128   // 2B
#define EPSF  1.1920928955078125e-07f

typedef __attribute__((ext_vector_type(8))) short   short8;
typedef __attribute__((ext_vector_type(4))) float   float4v;

__device__ __forceinline__ unsigned short f2bf(float f) {
  uint32_t x = __float_as_uint(f);
  x += 0x7FFFu + ((x >> 16) & 1u);          // RNE bf16
  return (unsigned short)(x >> 16);
}

// ---------------------------------------------------------------------------
// Kernel 1 (v2, LDS-free): transpose [B,C,H,W] f32 -> ws[hw][r][c] bf16 with
// 16B-chunk swizzle (data chunk c8 stored at slot (c8&~7)|(low3(c8)^ (r&7))).
// Each lane: 8 float2 loads (gathers 8 c at stride 4KB, 2 hw each), 16 cvt,
// two 16B stores. Per load instruction a wave touches 8 full 64B lines.
// ---------------------------------------------------------------------------
__global__ __launch_bounds__(256) void k_transpose(const float* __restrict__ inp,
                                                   const float* __restrict__ tgt,
                                                   unsigned short* __restrict__ wsF) {
  const int t   = threadIdx.x;
  const int j   = t & 7;          // chunk-within-group
  const int h   = (t >> 3) & 7;   // hw pair index
  const int g   = t >> 6;         // wave id = chunk group (0..3)
  const int r   = blockIdx.y;
  const int hw0 = blockIdx.x * 16;
  const int m   = r & 7;
  const int slot = g * 8 + j;           // destination 16B chunk (0..31)
  const int c8   = g * 8 + (j ^ m);     // source data chunk
  const float* src = (r < 64) ? (inp + (size_t)r * CCH * HWPOS)
                              : (tgt + (size_t)(r - 64) * CCH * HWPOS);
  const float* p = src + (size_t)c8 * 8 * HWPOS + hw0 + h * 2;
  float2 v[8];
#pragma unroll
  for (int e = 0; e < 8; ++e) v[e] = *(const float2*)(p + (size_t)e * HWPOS);
  uint4 oa, ob;
  oa.x = f2bf(v[0].x) | ((uint32_t)f2bf(v[1].x) << 16);
  oa.y = f2bf(v[2].x) | ((uint32_t)f2bf(v[3].x) << 16);
  oa.z = f2bf(v[4].x) | ((uint32_t)f2bf(v[5].x) << 16);
  oa.w = f2bf(v[6].x) | ((uint32_t)f2bf(v[7].x) << 16);
  ob.x = f2bf(v[0].y) | ((uint32_t)f2bf(v[1].y) << 16);
  ob.y = f2bf(v[2].y) | ((uint32_t)f2bf(v[3].y) << 16);
  ob.z = f2bf(v[4].y) | ((uint32_t)f2bf(v[5].y) << 16);
  ob.w = f2bf(v[6].y) | ((uint32_t)f2bf(v[7].y) << 16);
  const size_t ba = ((size_t)(hw0 + h * 2)     * RROWS + r) * CCH + slot * 8;
  const size_t bb = ((size_t)(hw0 + h * 2 + 1) * RROWS + r) * CCH + slot * 8;
  *(uint4*)(wsF + ba) = oa;
  *(uint4*)(wsF + bb) = ob;
}

// ---------------------------------------------------------------------------
// Kernel 2: one block per hw. Stage 64KB bf16 image via global_load_lds,
// gram via MFMA, norms from diagonal, fused masked log-softmax + pos extract.
// 8 waves; wave w owns G row-tile w (16 rows) x all 8 col-tiles.
// ---------------------------------------------------------------------------
__global__ __launch_bounds__(512, 4) void k_gram(const unsigned short* __restrict__ wsF,
                                                 float* __restrict__ partials) {
  __shared__ unsigned short Fs[RROWS * CCH];   // 64 KB, swizzled image
  __shared__ float sInv[RROWS];
  __shared__ float wred[8];
  const int t  = threadIdx.x;
  const int hw = blockIdx.x;
  // stage ws[hw] -> LDS: direct global->LDS DMA, 16B per lane, lane-ordered
  {
    const unsigned short* gsrc = wsF + (size_t)hw * (RROWS * CCH);
#pragma unroll
    for (int it = 0; it < 8; ++it) {
      __builtin_amdgcn_global_load_lds(
          (const __attribute__((address_space(1))) unsigned int*)(gsrc + (size_t)(it * 512 + t) * 8),
          (__attribute__((address_space(3))) unsigned int*)(Fs + (size_t)(it * 512 + t) * 8),
          16, 0, 0);
    }
  }
  __syncthreads();
  const int lane = t & 63;
  const int w    = t >> 6;        // wave id 0..7 = row-tile
  const int lid  = lane & 15;
  const int quad = lane >> 4;
  const int lm   = lid & 7;       // r&7 for every row this lane touches
  float4v acc[8];
#pragma unroll
  for (int ni = 0; ni < 8; ++ni) acc[ni] = (float4v){0.f, 0.f, 0.f, 0.f};
  const int baseA = ((w << 4) | lid) * CCH;
#pragma unroll
  for (int ks = 0; ks < 8; ++ks) {
    const int off = (((ks * 4 + quad) ^ lm) << 3);   // swizzled slot offset
    short8 a = *(const short8*)&Fs[baseA + off];
#pragma unroll
    for (int ni = 0; ni < 8; ++ni) {
      short8 b = *(const short8*)&Fs[((ni << 4) | lid) * CCH + off];
      acc[ni] = __builtin_amdgcn_mfma_f32_16x16x32_bf16(a, b, acc[ni], 0, 0, 0);
    }
  }
  // inverse norms from diag (tile ni==w; lanes with lid>>2 == quad hold it)
  if ((lid >> 2) == quad) {
    float nrm = fmaxf(sqrtf(acc[w][lid & 3]), EPSF);
    sInv[(w << 4) | lid] = 1.0f / nrm;
  }
  __syncthreads();
  float invj[8];
#pragma unroll
  for (int ni = 0; ni < 8; ++ni) invj[ni] = sInv[(ni << 4) | lid];
  float lacc = 0.f;
#pragma unroll
  for (int reg = 0; reg < 4; ++reg) {
    const int rloc = quad * 4 + reg;           // local row in tile
    const int rg   = (w << 4) | rloc;          // global row 0..127
    const float invi = sInv[rg];
    float v[8];
#pragma unroll
    for (int ni = 0; ni < 8; ++ni) v[ni] = 2.0f * acc[ni][reg] * invi * invj[ni];
    if (lid == rloc) v[w] = -3.0e38f;          // mask self-similarity
    float mx = v[0];
#pragma unroll
    for (int ni = 1; ni < 8; ++ni) mx = fmaxf(mx, v[ni]);
#pragma unroll
    for (int s = 1; s < 16; s <<= 1) mx = fmaxf(mx, __shfl_xor(mx, s, 16));
    float sm = 0.f;
#pragma unroll
    for (int ni = 0; ni < 8; ++ni) sm += __expf(v[ni] - mx);
#pragma unroll
    for (int s = 1; s < 16; s <<= 1) sm += __shfl_xor(sm, s, 16);
    const float lse = mx + __logf(sm);
    const int jp = (rg + 64) & 127;            // positive-pair column
    const float cand = v[jp >> 4];
    const float vp = __shfl(cand, jp & 15, 16);
    lacc += vp - lse;                          // log_softmax at partner (x16 lanes)
  }
#pragma unroll
  for (int s = 1; s < 64; s <<= 1) lacc += __shfl_xor(lacc, s, 64);
  if (lane == 0) wred[w] = lacc;
  __syncthreads();
  if (t == 0) {
    float tot = 0.f;
#pragma unroll
    for (int i = 0; i < 8; ++i) tot += wred[i];
    partials[hw] = tot;                        // = 16 * sum_rows(pos) for this hw
  }
}

// ---------------------------------------------------------------------------
// Kernel 3: reduce 1024 partials -> scalar loss
// ---------------------------------------------------------------------------
__global__ __launch_bounds__(256) void k_reduce(const float* __restrict__ partials,
                                                float* __restrict__ out) {
  __shared__ float wr[4];
  const int t = threadIdx.x;
  float s = 0.f;
#pragma unroll
  for (int i = 0; i < 4; ++i) s += partials[t + i * 256];
#pragma unroll
  for (int sh = 1; sh < 64; sh <<= 1) s += __shfl_xor(s, sh, 64);
  if ((t & 63) == 0) wr[t >> 6] = s;
  __syncthreads();
  if (t == 0) {
    out[0] = -(wr[0] + wr[1] + wr[2] + wr[3]) / (131072.0f * 16.0f);
  }
}

extern "C" void kernel_launch(void* const* d_in, const int* in_sizes, int n_in,
                              void* d_out, int out_size, void* d_ws, size_t ws_size,
                              hipStream_t stream) {
  const float* inp = (const float*)d_in[0];
  const float* tgt = (const float*)d_in[1];
  unsigned short* wsF = (unsigned short*)d_ws;
  float* partials = (float*)((char*)d_ws + (size_t)HWPOS * RROWS * CCH * 2);
  k_transpose<<<dim3(64, 128), 256, 0, stream>>>(inp, tgt, wsF);
  k_gram<<<dim3(HWPOS), 512, 0, stream>>>(wsF, partials);
  k_reduce<<<1, 256, 0, stream>>>(partials, (float*)d_out);
}

// Round 3
// 187.390 us; speedup vs baseline: 1.0525x; 1.0525x over previous
//
#include <hip/hip_runtime.h>
#include <stdint.h>

#define HWPOS 1024
#define CCH   256
#define RROWS 128   // 2B
#define EPSF  1.1920928955078125e-07f

typedef __attribute__((ext_vector_type(8))) short   short8;
typedef __attribute__((ext_vector_type(4))) float   float4v;

__device__ __forceinline__ unsigned short f2bf(float f) {
  uint32_t x = __float_as_uint(f);
  x += 0x7FFFu + ((x >> 16) & 1u);          // RNE bf16
  return (unsigned short)(x >> 16);
}

// ---------------------------------------------------------------------------
// Kernel 1 (v3): transpose [B,C,H,W] f32 -> ws[hw][r][c] bf16 with 16B-chunk
// swizzle (data chunk c8 stored at slot (c8&~7)|(low3(c8)^(r&7))).
// Block = one r x 32 hw x all 256 c. Lane: 8 float4 loads (8 c at 4KB stride,
// 4 hw each). Per wave-instruction: 8 FULL 128B granules -> no cross-XCD
// granule sharing (v2's 64B-per-block halved-granule reads doubled FETCH).
// ---------------------------------------------------------------------------
__global__ __launch_bounds__(256) void k_transpose(const float* __restrict__ inp,
                                                   const float* __restrict__ tgt,
                                                   unsigned short* __restrict__ wsF) {
  const int t   = threadIdx.x;
  const int j   = t & 7;          // chunk-within-group
  const int h4  = (t >> 3) & 7;   // hw quad index (4 hw each)
  const int g   = t >> 6;         // wave id = chunk group (0..3)
  const int r   = blockIdx.y;
  const int hw0 = blockIdx.x * 32;
  const int m   = r & 7;
  const int slot = g * 8 + j;           // destination 16B chunk (0..31)
  const int c8   = g * 8 + (j ^ m);     // source data chunk
  const float* src = (r < 64) ? (inp + (size_t)r * CCH * HWPOS)
                              : (tgt + (size_t)(r - 64) * CCH * HWPOS);
  const float* p = src + (size_t)c8 * 8 * HWPOS + hw0 + h4 * 4;
  float4 v[8];
#pragma unroll
  for (int e = 0; e < 8; ++e) v[e] = *(const float4*)(p + (size_t)e * HWPOS);
  // pack per-hw outputs: out[q] holds c-values e=0..7 for hw = hw0+h4*4+q
  uint4 o[4];
#pragma unroll
  for (int q = 0; q < 4; ++q) {
    float s0 = (q == 0) ? v[0].x : (q == 1) ? v[0].y : (q == 2) ? v[0].z : v[0].w;
    float s1 = (q == 0) ? v[1].x : (q == 1) ? v[1].y : (q == 2) ? v[1].z : v[1].w;
    float s2 = (q == 0) ? v[2].x : (q == 1) ? v[2].y : (q == 2) ? v[2].z : v[2].w;
    float s3 = (q == 0) ? v[3].x : (q == 1) ? v[3].y : (q == 2) ? v[3].z : v[3].w;
    float s4 = (q == 0) ? v[4].x : (q == 1) ? v[4].y : (q == 2) ? v[4].z : v[4].w;
    float s5 = (q == 0) ? v[5].x : (q == 1) ? v[5].y : (q == 2) ? v[5].z : v[5].w;
    float s6 = (q == 0) ? v[6].x : (q == 1) ? v[6].y : (q == 2) ? v[6].z : v[6].w;
    float s7 = (q == 0) ? v[7].x : (q == 1) ? v[7].y : (q == 2) ? v[7].z : v[7].w;
    o[q].x = f2bf(s0) | ((uint32_t)f2bf(s1) << 16);
    o[q].y = f2bf(s2) | ((uint32_t)f2bf(s3) << 16);
    o[q].z = f2bf(s4) | ((uint32_t)f2bf(s5) << 16);
    o[q].w = f2bf(s6) | ((uint32_t)f2bf(s7) << 16);
  }
#pragma unroll
  for (int q = 0; q < 4; ++q) {
    const size_t b = ((size_t)(hw0 + h4 * 4 + q) * RROWS + r) * CCH + slot * 8;
    *(uint4*)(wsF + b) = o[q];
  }
}

// ---------------------------------------------------------------------------
// Kernel 2: one block per hw. Stage 64KB bf16 image via global_load_lds,
// gram via MFMA, norms from diagonal, fused masked log-softmax + pos extract.
// 8 waves; wave w owns G row-tile w (16 rows) x all 8 col-tiles.
// ---------------------------------------------------------------------------
__global__ __launch_bounds__(512, 4) void k_gram(const unsigned short* __restrict__ wsF,
                                                 float* __restrict__ partials) {
  __shared__ unsigned short Fs[RROWS * CCH];   // 64 KB, swizzled image
  __shared__ float sInv[RROWS];
  __shared__ float wred[8];
  const int t  = threadIdx.x;
  const int hw = blockIdx.x;
  // stage ws[hw] -> LDS: direct global->LDS DMA, 16B per lane, lane-ordered
  {
    const unsigned short* gsrc = wsF + (size_t)hw * (RROWS * CCH);
#pragma unroll
    for (int it = 0; it < 8; ++it) {
      __builtin_amdgcn_global_load_lds(
          (const __attribute__((address_space(1))) unsigned int*)(gsrc + (size_t)(it * 512 + t) * 8),
          (__attribute__((address_space(3))) unsigned int*)(Fs + (size_t)(it * 512 + t) * 8),
          16, 0, 0);
    }
  }
  __syncthreads();
  const int lane = t & 63;
  const int w    = t >> 6;        // wave id 0..7 = row-tile
  const int lid  = lane & 15;
  const int quad = lane >> 4;
  const int lm   = lid & 7;       // r&7 for every row this lane touches
  float4v acc[8];
#pragma unroll
  for (int ni = 0; ni < 8; ++ni) acc[ni] = (float4v){0.f, 0.f, 0.f, 0.f};
  const int baseA = ((w << 4) | lid) * CCH;
#pragma unroll
  for (int ks = 0; ks < 8; ++ks) {
    const int off = (((ks * 4 + quad) ^ lm) << 3);   // swizzled slot offset
    short8 a = *(const short8*)&Fs[baseA + off];
#pragma unroll
    for (int ni = 0; ni < 8; ++ni) {
      short8 b = *(const short8*)&Fs[((ni << 4) | lid) * CCH + off];
      acc[ni] = __builtin_amdgcn_mfma_f32_16x16x32_bf16(a, b, acc[ni], 0, 0, 0);
    }
  }
  // inverse norms from diag (tile ni==w; lanes with lid>>2 == quad hold it)
  if ((lid >> 2) == quad) {
    float nrm = fmaxf(sqrtf(acc[w][lid & 3]), EPSF);
    sInv[(w << 4) | lid] = 1.0f / nrm;
  }
  __syncthreads();
  float invj[8];
#pragma unroll
  for (int ni = 0; ni < 8; ++ni) invj[ni] = sInv[(ni << 4) | lid];
  float lacc = 0.f;
#pragma unroll
  for (int reg = 0; reg < 4; ++reg) {
    const int rloc = quad * 4 + reg;           // local row in tile
    const int rg   = (w << 4) | rloc;          // global row 0..127
    const float invi = sInv[rg];
    float v[8];
#pragma unroll
    for (int ni = 0; ni < 8; ++ni) v[ni] = 2.0f * acc[ni][reg] * invi * invj[ni];
    if (lid == rloc) v[w] = -3.0e38f;          // mask self-similarity
    float mx = v[0];
#pragma unroll
    for (int ni = 1; ni < 8; ++ni) mx = fmaxf(mx, v[ni]);
#pragma unroll
    for (int s = 1; s < 16; s <<= 1) mx = fmaxf(mx, __shfl_xor(mx, s, 16));
    float sm = 0.f;
#pragma unroll
    for (int ni = 0; ni < 8; ++ni) sm += __expf(v[ni] - mx);
#pragma unroll
    for (int s = 1; s < 16; s <<= 1) sm += __shfl_xor(sm, s, 16);
    const float lse = mx + __logf(sm);
    const int jp = (rg + 64) & 127;            // positive-pair column
    const float cand = v[jp >> 4];
    const float vp = __shfl(cand, jp & 15, 16);
    lacc += vp - lse;                          // log_softmax at partner (x16 lanes)
  }
#pragma unroll
  for (int s = 1; s < 64; s <<= 1) lacc += __shfl_xor(lacc, s, 64);
  if (lane == 0) wred[w] = lacc;
  __syncthreads();
  if (t == 0) {
    float tot = 0.f;
#pragma unroll
    for (int i = 0; i < 8; ++i) tot += wred[i];
    partials[hw] = tot;                        // = 16 * sum_rows(pos) for this hw
  }
}

// ---------------------------------------------------------------------------
// Kernel 3: reduce 1024 partials -> scalar loss
// ---------------------------------------------------------------------------
__global__ __launch_bounds__(256) void k_reduce(const float* __restrict__ partials,
                                                float* __restrict__ out) {
  __shared__ float wr[4];
  const int t = threadIdx.x;
  float s = 0.f;
#pragma unroll
  for (int i = 0; i < 4; ++i) s += partials[t + i * 256];
#pragma unroll
  for (int sh = 1; sh < 64; sh <<= 1) s += __shfl_xor(s, sh, 64);
  if ((t & 63) == 0) wr[t >> 6] = s;
  __syncthreads();
  if (t == 0) {
    out[0] = -(wr[0] + wr[1] + wr[2] + wr[3]) / (131072.0f * 16.0f);
  }
}

extern "C" void kernel_launch(void* const* d_in, const int* in_sizes, int n_in,
                              void* d_out, int out_size, void* d_ws, size_t ws_size,
                              hipStream_t stream) {
  const float* inp = (const float*)d_in[0];
  const float* tgt = (const float*)d_in[1];
  unsigned short* wsF = (unsigned short*)d_ws;
  float* partials = (float*)((char*)d_ws + (size_t)HWPOS * RROWS * CCH * 2);
  k_transpose<<<dim3(32, 128), 256, 0, stream>>>(inp, tgt, wsF);
  k_gram<<<dim3(HWPOS), 512, 0, stream>>>(wsF, partials);
  k_reduce<<<1, 256, 0, stream>>>(partials, (float*)d_out);
}